// Round 3
// baseline (104.907 us; speedup 1.0000x reference)
//
#include <hip/hip_runtime.h>
#include <hip/hip_bf16.h>
#include <math.h>

// Problem constants: NUM_TILES=32, N_HEAD=4 (folds away), D_MODEL=256, B=4
#define TT   1024
#define DD   256
#define KN   63
#define BB   4
#define MM   (BB * TT)

typedef short bf16x8 __attribute__((ext_vector_type(8)));   // 8 bf16 = 4 VGPRs
typedef float f32x4  __attribute__((ext_vector_type(4)));

__device__ __forceinline__ unsigned short bf16bits(float f) {
    __hip_bfloat16 h = __float2bfloat16(f);
    return *reinterpret_cast<unsigned short*>(&h);
}
__device__ __forceinline__ float bf16tof(unsigned short u) {
    __hip_bfloat16 h;
    *reinterpret_cast<unsigned short*>(&h) = u;
    return __bfloat162float(h);
}
__device__ __forceinline__ void split4(float4 v, ushort4& h, ushort4& l) {
    float vf[4] = {v.x, v.y, v.z, v.w};
    unsigned short* hp = &h.x;
    unsigned short* lp = &l.x;
    #pragma unroll
    for (int i = 0; i < 4; ++i) {
        unsigned short b = bf16bits(vf[i]);
        hp[i] = b;
        lp[i] = bf16bits(vf[i] - bf16tof(b));
    }
}

// ---------------------------------------------------------------------------
// proj_mfma: y = x @ Wcat^T via split-bf16 MFMA (xh*Wh + xh*Wl + xl*Wh).
// f32->bf16 hi/lo split done INLINE during LDS staging (no prep pass).
// 64x64 tile, BK=32, grid (64, 12) = 768 blocks (3/CU), 4 waves as 2x2
// quadrants of 32x32, mfma_f32_16x16x32_bf16.
// LDS per tensor: [64 rows][4 k-slots of 16B], slot XOR (row&3) swizzle:
// ds_read_b128 fragment reads and ds_write_b64 staging are both conflict-free.
// Epilogue: ny 0-3 -> P=sigmoid, 4-7 -> E=exp, 8-11 -> V raw.
// ---------------------------------------------------------------------------
__global__ __launch_bounds__(256) void proj_mfma(
    const float* __restrict__ x,  const float* __restrict__ Wq,
    const float* __restrict__ Wk, const float* __restrict__ Wv,
    float* __restrict__ P, float* __restrict__ E, float* __restrict__ V)
{
    __shared__ char lds[16384];          // xh | xl | Wh | Wl, 4KB each
    const int tid  = threadIdx.x;
    const int lane = tid & 63, wave = tid >> 6;
    const int wr = wave >> 1, wc = wave & 1;
    const int m0 = blockIdx.x * 64;
    const int ny = blockIdx.y;           // 0..11
    const int region = ny >> 2;          // 0=q,1=k,2=v
    const float* __restrict__ Ws = (region == 0) ? Wq : (region == 1) ? Wk : Wv;
    const int w0 = (ny & 3) * 64;        // row offset within Ws

    f32x4 acc[2][2];
    #pragma unroll
    for (int i = 0; i < 2; ++i)
        #pragma unroll
        for (int j = 0; j < 2; ++j) acc[i][j] = (f32x4)0.0f;

    const int li = lane & 15, kg = lane >> 4;

    for (int kt = 0; kt < 8; ++kt) {
        const int k0 = kt * 32;
        #pragma unroll
        for (int i = 0; i < 2; ++i) {
            const int s   = tid + i * 256;   // 0..511
            const int row = s >> 3;          // 0..63
            const int q   = s & 7;           // 4-f32 chunk within 32-k row
            float4 a = *reinterpret_cast<const float4*>(
                &x[(size_t)(m0 + row) * DD + k0 + q * 4]);
            float4 b = *reinterpret_cast<const float4*>(
                &Ws[(size_t)(w0 + row) * DD + k0 + q * 4]);
            ushort4 xh_, xl_, wh_, wl_;
            split4(a, xh_, xl_);
            split4(b, wh_, wl_);
            const int off = row * 64 + ((((q >> 1)) ^ (row & 3)) << 4) + (q & 1) * 8;
            *reinterpret_cast<ushort4*>(lds + off)         = xh_;
            *reinterpret_cast<ushort4*>(lds + 4096  + off) = xl_;
            *reinterpret_cast<ushort4*>(lds + 8192  + off) = wh_;
            *reinterpret_cast<ushort4*>(lds + 12288 + off) = wl_;
        }
        __syncthreads();

        bf16x8 bh[2], bl[2];
        #pragma unroll
        for (int fn = 0; fn < 2; ++fn) {
            const int r   = wc * 32 + fn * 16 + li;
            const int off = r * 64 + ((kg ^ (r & 3)) << 4);
            bh[fn] = *reinterpret_cast<const bf16x8*>(lds + 8192  + off);
            bl[fn] = *reinterpret_cast<const bf16x8*>(lds + 12288 + off);
        }
        #pragma unroll
        for (int fm = 0; fm < 2; ++fm) {
            const int r   = wr * 32 + fm * 16 + li;
            const int off = r * 64 + ((kg ^ (r & 3)) << 4);
            bf16x8 ah = *reinterpret_cast<const bf16x8*>(lds + off);
            bf16x8 al = *reinterpret_cast<const bf16x8*>(lds + 4096 + off);
            #pragma unroll
            for (int fn = 0; fn < 2; ++fn) {
                acc[fm][fn] = __builtin_amdgcn_mfma_f32_16x16x32_bf16(ah, bh[fn], acc[fm][fn], 0, 0, 0);
                acc[fm][fn] = __builtin_amdgcn_mfma_f32_16x16x32_bf16(ah, bl[fn], acc[fm][fn], 0, 0, 0);
                acc[fm][fn] = __builtin_amdgcn_mfma_f32_16x16x32_bf16(al, bh[fn], acc[fm][fn], 0, 0, 0);
            }
        }
        __syncthreads();
    }

    // Epilogue. C/D layout: col=lane&15, row=(lane>>4)*4+j (verified mapping).
    float* __restrict__ ob = (region == 0) ? P : (region == 1) ? E : V;
    const int colbase = (ny & 3) * 64 + wc * 32;
    #pragma unroll
    for (int fm = 0; fm < 2; ++fm) {
        #pragma unroll
        for (int fn = 0; fn < 2; ++fn) {
            const int rb = m0 + wr * 32 + fm * 16 + kg * 4;
            const int cc = colbase + fn * 16 + li;
            #pragma unroll
            for (int j = 0; j < 4; ++j) {
                float v0 = acc[fm][fn][j];
                if (region == 0)      v0 = 1.0f / (1.0f + __expf(-v0));
                else if (region == 1) v0 = __expf(v0);
                ob[(size_t)(rb + j) * DD + cc] = v0;
            }
        }
    }
}

// ---------------------------------------------------------------------------
// rowpass: block = (b, r, d-half). Builds the 32x32 row-weight tile inline
// from wbias/key_indices (row entries cover all 32 slots -> no zero init).
// num/den over the 32 tokens of grid row r; num -> d_out, den -> Dbuf.
// ---------------------------------------------------------------------------
__global__ __launch_bounds__(256) void rowpass(
    const float* __restrict__ E, const float* __restrict__ V,
    const float* __restrict__ wbias, const int* __restrict__ kidx,
    float* __restrict__ Nout, float* __restrict__ Dout)
{
    __shared__ float Et[32][132], Vt[32][132], At[32][33];
    const int bid = blockIdx.x, tid = threadIdx.x;
    const int dh = bid & 1, r = (bid >> 1) & 31, b = bid >> 6;
    const size_t base = ((size_t)(b * TT + r * 32)) * DD + dh * 128;

    #pragma unroll
    for (int i = 0; i < 4; ++i) {
        const int slot = tid + i * 256;
        const int row = slot >> 5, c4 = (slot & 31) * 4;
        *reinterpret_cast<f32x4*>(&Et[row][c4]) =
            *reinterpret_cast<const f32x4*>(&E[base + (size_t)row * DD + c4]);
        *reinterpret_cast<f32x4*>(&Vt[row][c4]) =
            *reinterpret_cast<const f32x4*>(&V[base + (size_t)row * DD + c4]);
    }
    // Inline row-weight build: entry e -> token col c=e/63, list pos k=e%63.
    for (int e = tid; e < 32 * KN; e += 256) {
        const int c = e / KN, k = e - c * KN;
        const int t = r * 32 + c;
        const int idx = kidx[t * KN + k];
        if ((idx >> 5) == r) At[c][idx & 31] = __expf(wbias[t * KN + k]);
    }
    __syncthreads();

    const int dq = tid & 31, cg = tid >> 5;
    f32x4 num[4], den[4];
    #pragma unroll
    for (int ci = 0; ci < 4; ++ci) { num[ci] = (f32x4)0.0f; den[ci] = (f32x4)0.0f; }

    for (int j = 0; j < 32; ++j) {
        f32x4 e = *reinterpret_cast<const f32x4*>(&Et[j][dq * 4]);
        f32x4 v = *reinterpret_cast<const f32x4*>(&Vt[j][dq * 4]);
        f32x4 ev = e * v;
        #pragma unroll
        for (int ci = 0; ci < 4; ++ci) {
            const float w = At[cg * 4 + ci][j];
            den[ci] += e * w;
            num[ci] += ev * w;
        }
    }
    #pragma unroll
    for (int ci = 0; ci < 4; ++ci) {
        const size_t o = ((size_t)(b * TT + r * 32 + cg * 4 + ci)) * DD + dh * 128 + dq * 4;
        *reinterpret_cast<f32x4*>(&Nout[o]) = num[ci];
        *reinterpret_cast<f32x4*>(&Dout[o]) = den[ci];
    }
}

// ---------------------------------------------------------------------------
// colpass: block = (b, c, d-half). Builds the 32x32 col-weight tile inline
// (diagonal excluded -> zero-init + scatter), adds column partials, fuses
// out = P * (numR+numC) / (denR+denC) in place on d_out.
// ---------------------------------------------------------------------------
__global__ __launch_bounds__(256) void colpass(
    const float* __restrict__ E, const float* __restrict__ V,
    const float* __restrict__ wbias, const int* __restrict__ kidx,
    const float* __restrict__ P, const float* __restrict__ Drow,
    float* __restrict__ out)
{
    __shared__ float Et[32][132], Vt[32][132], Bt[32][33];
    const int bid = blockIdx.x, tid = threadIdx.x;
    const int dh = bid & 1, c = (bid >> 1) & 31, b = bid >> 6;

    #pragma unroll
    for (int i = 0; i < 4; ++i) {
        const int slot = tid + i * 256;
        const int j = slot >> 5, c4 = (slot & 31) * 4;
        const size_t g = ((size_t)(b * TT + j * 32 + c)) * DD + dh * 128 + c4;
        *reinterpret_cast<f32x4*>(&Et[j][c4]) = *reinterpret_cast<const f32x4*>(&E[g]);
        *reinterpret_cast<f32x4*>(&Vt[j][c4]) = *reinterpret_cast<const f32x4*>(&V[g]);
    }
    for (int e = tid; e < 32 * 33; e += 256) (&Bt[0][0])[e] = 0.0f;
    __syncthreads();

    // Col entries of token t=(rp,c) are idx = c + 32*j, j != rp.
    for (int e = tid; e < 32 * KN; e += 256) {
        const int rp = e / KN, k = e - rp * KN;
        const int t = rp * 32 + c;
        const int idx = kidx[t * KN + k];
        const int ir = idx >> 5;
        if (ir != rp) Bt[rp][ir] = __expf(wbias[t * KN + k]);
    }
    __syncthreads();

    const int dq = tid & 31, rg = tid >> 5;
    f32x4 num[4], den[4];
    #pragma unroll
    for (int ri = 0; ri < 4; ++ri) { num[ri] = (f32x4)0.0f; den[ri] = (f32x4)0.0f; }

    for (int j = 0; j < 32; ++j) {
        f32x4 e = *reinterpret_cast<const f32x4*>(&Et[j][dq * 4]);
        f32x4 v = *reinterpret_cast<const f32x4*>(&Vt[j][dq * 4]);
        f32x4 ev = e * v;
        #pragma unroll
        for (int ri = 0; ri < 4; ++ri) {
            const float w = Bt[rg * 4 + ri][j];
            den[ri] += e * w;
            num[ri] += ev * w;
        }
    }
    #pragma unroll
    for (int ri = 0; ri < 4; ++ri) {
        const size_t o = ((size_t)(b * TT + (rg * 4 + ri) * 32 + c)) * DD + dh * 128 + dq * 4;
        f32x4 nr = *reinterpret_cast<const f32x4*>(&out[o]);
        f32x4 dr = *reinterpret_cast<const f32x4*>(&Drow[o]);
        f32x4 p  = *reinterpret_cast<const f32x4*>(&P[o]);
        f32x4 res = p * (num[ri] + nr) / (den[ri] + dr);
        *reinterpret_cast<f32x4*>(&out[o]) = res;
    }
}

extern "C" void kernel_launch(void* const* d_in, const int* in_sizes, int n_in,
                              void* d_out, int out_size, void* d_ws, size_t ws_size,
                              hipStream_t stream) {
    const float* x     = (const float*)d_in[0];
    const float* Wq    = (const float*)d_in[1];
    const float* Wk    = (const float*)d_in[2];
    const float* Wv    = (const float*)d_in[3];
    const float* wbias = (const float*)d_in[4];
    const int*   kidx  = (const int*)d_in[5];

    float* P    = (float*)d_ws;        // 4 MB
    float* E    = P + 1048576;         // 4 MB
    float* V    = E + 1048576;         // 4 MB
    float* Dbuf = V + 1048576;         // 4 MB

    proj_mfma<<<dim3(64, 12), 256, 0, stream>>>(x, Wq, Wk, Wv, P, E, V);
    rowpass<<<256, 256, 0, stream>>>(E, V, wbias, kidx, (float*)d_out, Dbuf);
    colpass<<<256, 256, 0, stream>>>(E, V, wbias, kidx, P, Dbuf, (float*)d_out);
}

// Round 4
// 102.646 us; speedup vs baseline: 1.0220x; 1.0220x over previous
//
#include <hip/hip_runtime.h>
#include <hip/hip_bf16.h>
#include <math.h>

// Problem constants: NUM_TILES=32, N_HEAD=4 (folds away), D_MODEL=256, B=4
#define TT   1024
#define DD   256
#define KN   63
#define BB   4
#define MM   (BB * TT)

typedef short bf16x8 __attribute__((ext_vector_type(8)));   // 8 bf16 = 4 VGPRs
typedef float f32x4  __attribute__((ext_vector_type(4)));

__device__ __forceinline__ unsigned short bf16bits(float f) {
    __hip_bfloat16 h = __float2bfloat16(f);
    return *reinterpret_cast<unsigned short*>(&h);
}
__device__ __forceinline__ float bf16tof(unsigned short u) {
    __hip_bfloat16 h;
    *reinterpret_cast<unsigned short*>(&h) = u;
    return __bfloat162float(h);
}
__device__ __forceinline__ void split4(float4 v, ushort4& h, ushort4& l) {
    float vf[4] = {v.x, v.y, v.z, v.w};
    unsigned short* hp = &h.x;
    unsigned short* lp = &l.x;
    #pragma unroll
    for (int i = 0; i < 4; ++i) {
        unsigned short b = bf16bits(vf[i]);
        hp[i] = b;
        lp[i] = bf16bits(vf[i] - bf16tof(b));
    }
}

// ---------------------------------------------------------------------------
// proj_mfma: y = x @ Wcat^T via split-bf16 MFMA (xh*Wh + xh*Wl + xl*Wh).
// Unchanged from R3 (passed, ~4 us). 64x64 tile, BK=32, grid (64,12),
// inline f32->bf16 hi/lo split during LDS staging, XOR k-slot swizzle.
// Epilogue: ny 0-3 -> P=sigmoid, 4-7 -> E=exp, 8-11 -> V raw.
// ---------------------------------------------------------------------------
__global__ __launch_bounds__(256) void proj_mfma(
    const float* __restrict__ x,  const float* __restrict__ Wq,
    const float* __restrict__ Wk, const float* __restrict__ Wv,
    float* __restrict__ P, float* __restrict__ E, float* __restrict__ V)
{
    __shared__ char lds[16384];          // xh | xl | Wh | Wl, 4KB each
    const int tid  = threadIdx.x;
    const int lane = tid & 63, wave = tid >> 6;
    const int wr = wave >> 1, wc = wave & 1;
    const int m0 = blockIdx.x * 64;
    const int ny = blockIdx.y;           // 0..11
    const int region = ny >> 2;          // 0=q,1=k,2=v
    const float* __restrict__ Ws = (region == 0) ? Wq : (region == 1) ? Wk : Wv;
    const int w0 = (ny & 3) * 64;

    f32x4 acc[2][2];
    #pragma unroll
    for (int i = 0; i < 2; ++i)
        #pragma unroll
        for (int j = 0; j < 2; ++j) acc[i][j] = (f32x4)0.0f;

    const int li = lane & 15, kg = lane >> 4;

    for (int kt = 0; kt < 8; ++kt) {
        const int k0 = kt * 32;
        #pragma unroll
        for (int i = 0; i < 2; ++i) {
            const int s   = tid + i * 256;
            const int row = s >> 3;
            const int q   = s & 7;
            float4 a = *reinterpret_cast<const float4*>(
                &x[(size_t)(m0 + row) * DD + k0 + q * 4]);
            float4 b = *reinterpret_cast<const float4*>(
                &Ws[(size_t)(w0 + row) * DD + k0 + q * 4]);
            ushort4 xh_, xl_, wh_, wl_;
            split4(a, xh_, xl_);
            split4(b, wh_, wl_);
            const int off = row * 64 + ((((q >> 1)) ^ (row & 3)) << 4) + (q & 1) * 8;
            *reinterpret_cast<ushort4*>(lds + off)         = xh_;
            *reinterpret_cast<ushort4*>(lds + 4096  + off) = xl_;
            *reinterpret_cast<ushort4*>(lds + 8192  + off) = wh_;
            *reinterpret_cast<ushort4*>(lds + 12288 + off) = wl_;
        }
        __syncthreads();

        bf16x8 bh[2], bl[2];
        #pragma unroll
        for (int fn = 0; fn < 2; ++fn) {
            const int r   = wc * 32 + fn * 16 + li;
            const int off = r * 64 + ((kg ^ (r & 3)) << 4);
            bh[fn] = *reinterpret_cast<const bf16x8*>(lds + 8192  + off);
            bl[fn] = *reinterpret_cast<const bf16x8*>(lds + 12288 + off);
        }
        #pragma unroll
        for (int fm = 0; fm < 2; ++fm) {
            const int r   = wr * 32 + fm * 16 + li;
            const int off = r * 64 + ((kg ^ (r & 3)) << 4);
            bf16x8 ah = *reinterpret_cast<const bf16x8*>(lds + off);
            bf16x8 al = *reinterpret_cast<const bf16x8*>(lds + 4096 + off);
            #pragma unroll
            for (int fn = 0; fn < 2; ++fn) {
                acc[fm][fn] = __builtin_amdgcn_mfma_f32_16x16x32_bf16(ah, bh[fn], acc[fm][fn], 0, 0, 0);
                acc[fm][fn] = __builtin_amdgcn_mfma_f32_16x16x32_bf16(ah, bl[fn], acc[fm][fn], 0, 0, 0);
                acc[fm][fn] = __builtin_amdgcn_mfma_f32_16x16x32_bf16(al, bh[fn], acc[fm][fn], 0, 0, 0);
            }
        }
        __syncthreads();
    }

    float* __restrict__ ob = (region == 0) ? P : (region == 1) ? E : V;
    const int colbase = (ny & 3) * 64 + wc * 32;
    #pragma unroll
    for (int fm = 0; fm < 2; ++fm) {
        #pragma unroll
        for (int fn = 0; fn < 2; ++fn) {
            const int rb = m0 + wr * 32 + fm * 16 + kg * 4;
            const int cc = colbase + fn * 16 + li;
            #pragma unroll
            for (int j = 0; j < 4; ++j) {
                float v0 = acc[fm][fn][j];
                if (region == 0)      v0 = 1.0f / (1.0f + __expf(-v0));
                else if (region == 1) v0 = __expf(v0);
                ob[(size_t)(rb + j) * DD + cc] = v0;
            }
        }
    }
}

// ---------------------------------------------------------------------------
// rowpass: block = (b, r, d-quarter). 512 blocks (2/CU) for TLP. Builds the
// 32x32 row-weight tile inline (row entries cover all 32 slots, no init).
// num -> d_out, den -> Dbuf.
// Thread map: dqi = tid&15 (f32x4 chunk of the 64-wide d slice),
//             cg = tid>>4 (0..15), each thread owns tokens c = cg*2, cg*2+1.
// ---------------------------------------------------------------------------
__global__ __launch_bounds__(256) void rowpass(
    const float* __restrict__ E, const float* __restrict__ V,
    const float* __restrict__ wbias, const int* __restrict__ kidx,
    float* __restrict__ Nout, float* __restrict__ Dout)
{
    __shared__ float Et[32][68], Vt[32][68], At[32][33];
    const int bid = blockIdx.x, tid = threadIdx.x;
    const int dq = bid & 3, r = (bid >> 2) & 31, b = bid >> 7;
    const size_t base = ((size_t)(b * TT + r * 32)) * DD + dq * 64;

    #pragma unroll
    for (int i = 0; i < 2; ++i) {
        const int s = tid + i * 256;
        const int row = s >> 4, c4 = (s & 15) * 4;
        *reinterpret_cast<f32x4*>(&Et[row][c4]) =
            *reinterpret_cast<const f32x4*>(&E[base + (size_t)row * DD + c4]);
        *reinterpret_cast<f32x4*>(&Vt[row][c4]) =
            *reinterpret_cast<const f32x4*>(&V[base + (size_t)row * DD + c4]);
    }
    // Inline row-weight build: entry e -> token col c=e/63, list pos k=e%63.
    for (int e = tid; e < 32 * KN; e += 256) {
        const int c = e / KN, k = e - c * KN;
        const int t = r * 32 + c;
        const int idx = kidx[t * KN + k];
        if ((idx >> 5) == r) At[c][idx & 31] = __expf(wbias[t * KN + k]);
    }
    __syncthreads();

    const int dqi = tid & 15, cg = tid >> 4;
    f32x4 num[2], den[2];
    #pragma unroll
    for (int ci = 0; ci < 2; ++ci) { num[ci] = (f32x4)0.0f; den[ci] = (f32x4)0.0f; }

    for (int j = 0; j < 32; ++j) {
        f32x4 e = *reinterpret_cast<const f32x4*>(&Et[j][dqi * 4]);
        f32x4 v = *reinterpret_cast<const f32x4*>(&Vt[j][dqi * 4]);
        f32x4 ev = e * v;
        #pragma unroll
        for (int ci = 0; ci < 2; ++ci) {
            const float w = At[cg * 2 + ci][j];
            den[ci] += e * w;
            num[ci] += ev * w;
        }
    }
    #pragma unroll
    for (int ci = 0; ci < 2; ++ci) {
        const size_t o = ((size_t)(b * TT + r * 32 + cg * 2 + ci)) * DD + dq * 64 + dqi * 4;
        *reinterpret_cast<f32x4*>(&Nout[o]) = num[ci];
        *reinterpret_cast<f32x4*>(&Dout[o]) = den[ci];
    }
}

// ---------------------------------------------------------------------------
// colpass: block = (b, c, d-quarter). 512 blocks (2/CU). Builds the 32x32
// col-weight tile inline (diagonal excluded: zero-init + scatter), adds the
// column partials, fuses out = P*(numR+numC)/(denR+denC) in place on d_out.
// ---------------------------------------------------------------------------
__global__ __launch_bounds__(256) void colpass(
    const float* __restrict__ E, const float* __restrict__ V,
    const float* __restrict__ wbias, const int* __restrict__ kidx,
    const float* __restrict__ P, const float* __restrict__ Drow,
    float* __restrict__ out)
{
    __shared__ float Et[32][68], Vt[32][68], Bt[32][33];
    const int bid = blockIdx.x, tid = threadIdx.x;
    const int dq = bid & 3, c = (bid >> 2) & 31, b = bid >> 7;

    #pragma unroll
    for (int i = 0; i < 2; ++i) {
        const int s = tid + i * 256;
        const int j = s >> 4, c4 = (s & 15) * 4;
        const size_t g = ((size_t)(b * TT + j * 32 + c)) * DD + dq * 64 + c4;
        *reinterpret_cast<f32x4*>(&Et[j][c4]) = *reinterpret_cast<const f32x4*>(&E[g]);
        *reinterpret_cast<f32x4*>(&Vt[j][c4]) = *reinterpret_cast<const f32x4*>(&V[g]);
    }
    for (int e = tid; e < 32 * 33; e += 256) (&Bt[0][0])[e] = 0.0f;
    __syncthreads();

    // Col entries of token t=(rp,c) are idx = c + 32*j, j != rp.
    for (int e = tid; e < 32 * KN; e += 256) {
        const int rp = e / KN, k = e - rp * KN;
        const int t = rp * 32 + c;
        const int idx = kidx[t * KN + k];
        const int ir = idx >> 5;
        if (ir != rp) Bt[rp][ir] = __expf(wbias[t * KN + k]);
    }
    __syncthreads();

    const int dqi = tid & 15, cg = tid >> 4;
    f32x4 num[2], den[2];
    #pragma unroll
    for (int ri = 0; ri < 2; ++ri) { num[ri] = (f32x4)0.0f; den[ri] = (f32x4)0.0f; }

    for (int j = 0; j < 32; ++j) {
        f32x4 e = *reinterpret_cast<const f32x4*>(&Et[j][dqi * 4]);
        f32x4 v = *reinterpret_cast<const f32x4*>(&Vt[j][dqi * 4]);
        f32x4 ev = e * v;
        #pragma unroll
        for (int ri = 0; ri < 2; ++ri) {
            const float w = Bt[cg * 2 + ri][j];
            den[ri] += e * w;
            num[ri] += ev * w;
        }
    }
    #pragma unroll
    for (int ri = 0; ri < 2; ++ri) {
        const size_t o = ((size_t)(b * TT + (cg * 2 + ri) * 32 + c)) * DD + dq * 64 + dqi * 4;
        f32x4 nr = *reinterpret_cast<const f32x4*>(&out[o]);
        f32x4 dr = *reinterpret_cast<const f32x4*>(&Drow[o]);
        f32x4 p  = *reinterpret_cast<const f32x4*>(&P[o]);
        f32x4 res = p * (num[ri] + nr) / (den[ri] + dr);
        *reinterpret_cast<f32x4*>(&out[o]) = res;
    }
}

extern "C" void kernel_launch(void* const* d_in, const int* in_sizes, int n_in,
                              void* d_out, int out_size, void* d_ws, size_t ws_size,
                              hipStream_t stream) {
    const float* x     = (const float*)d_in[0];
    const float* Wq    = (const float*)d_in[1];
    const float* Wk    = (const float*)d_in[2];
    const float* Wv    = (const float*)d_in[3];
    const float* wbias = (const float*)d_in[4];
    const int*   kidx  = (const int*)d_in[5];

    float* P    = (float*)d_ws;        // 4 MB
    float* E    = P + 1048576;         // 4 MB
    float* V    = E + 1048576;         // 4 MB
    float* Dbuf = V + 1048576;         // 4 MB

    proj_mfma<<<dim3(64, 12), 256, 0, stream>>>(x, Wq, Wk, Wv, P, E, V);
    rowpass<<<512, 256, 0, stream>>>(E, V, wbias, kidx, (float*)d_out, Dbuf);
    colpass<<<512, 256, 0, stream>>>(E, V, wbias, kidx, P, Dbuf, (float*)d_out);
}